// Round 1
// baseline (926.969 us; speedup 1.0000x reference)
//
#include <hip/hip_runtime.h>
#include <hip/hip_bf16.h>
#include <math.h>

typedef unsigned short u16;
typedef unsigned int u32;

constexpr int NB = 64, NS = 128, NDM = 1024, NH = 16, NDK = 64;
constexpr int NM = NB * NS;           // 8192 rows (B*S)
constexpr float QEPS = 1e-8f;

typedef __attribute__((ext_vector_type(8))) short short8;
typedef __attribute__((ext_vector_type(4))) float f32x4;

// ---- ordered-uint encoding so atomicMax(u32) == float max (handles negatives) ----
__device__ __forceinline__ u32 fenc(float f) {
  u32 u = __float_as_uint(f);
  return (u & 0x80000000u) ? ~u : (u | 0x80000000u);
}
__device__ __forceinline__ float fdec(u32 u) {
  u = (u & 0x80000000u) ? (u & 0x7FFFFFFFu) : ~u;
  return __uint_as_float(u);
}
// our quantized values are small integers -> low mantissa bits are zero -> exact truncation
__device__ __forceinline__ u16 f2bf(float f) { return (u16)(__float_as_uint(f) >> 16); }
__device__ __forceinline__ float bf2f(u16 u) { return __uint_as_float(((u32)u) << 16); }

// ---------------- scale-slot layout (floats at ws offset 0) ----------------
// [0] enc max(query) [1] enc max(key) [2] enc max(value)
// [3..6] enc absmax(Wq,Wk,Wv,Wo)  [7] enc max(x_attnout)
// [8..135]   absmax_q per s (plain float)
// [136..263] absmax_k per s
// [264..391] absmax_v per s
// [392..519] max_p per j (plain float bits, int-atomic, p>0)

__global__ void init_kernel(u32* scl) {
  for (int i = threadIdx.x; i < 2048; i += blockDim.x) scl[i] = 0u;
}

__global__ void reduce_max_kernel(const float* __restrict__ src, size_t n,
                                  u32* __restrict__ slot, int useAbs) {
  float m = -INFINITY;
  size_t stride = (size_t)gridDim.x * blockDim.x;
  for (size_t i = (size_t)blockIdx.x * blockDim.x + threadIdx.x; i < n; i += stride) {
    float v = src[i];
    if (useAbs) v = fabsf(v);
    m = fmaxf(m, v);
  }
  for (int off = 32; off; off >>= 1) m = fmaxf(m, __shfl_down(m, off));
  __shared__ float sm[8];
  int lane = threadIdx.x & 63, wid = threadIdx.x >> 6;
  if (lane == 0) sm[wid] = m;
  __syncthreads();
  if (threadIdx.x == 0) {
    float r = sm[0];
    for (int i = 1; i < (int)(blockDim.x >> 6); i++) r = fmaxf(r, sm[i]);
    atomicMax(slot, fenc(r));
  }
}

// uint8 activation fake-quant -> bf16 integer grid (0..255)
__global__ void quant_u8_kernel(const float* __restrict__ src, u16* __restrict__ dst,
                                size_t n, const u32* __restrict__ slot) {
  float s = fmaxf(fdec(*slot), QEPS) / 255.0f;
  size_t stride = (size_t)gridDim.x * blockDim.x;
  for (size_t i = (size_t)blockIdx.x * blockDim.x + threadIdx.x; i < n; i += stride) {
    float q = fminf(fmaxf(rintf(src[i] / s), 0.0f), 255.0f);
    dst[i] = f2bf(q);
  }
}

// int8 weight fake-quant (narrow range) -> bf16 integer grid (-127..127)
__global__ void quant_w_kernel(const float* __restrict__ src, u16* __restrict__ dst,
                               size_t n, const u32* __restrict__ slot) {
  float s = fmaxf(fdec(*slot), QEPS) / 127.0f;
  size_t stride = (size_t)gridDim.x * blockDim.x;
  for (size_t i = (size_t)blockIdx.x * blockDim.x + threadIdx.x; i < n; i += stride) {
    float q = fminf(fmaxf(rintf(src[i] / s), -127.0f), 127.0f);
    dst[i] = f2bf(q);
  }
}

// ---------------- GEMM: C[m,n] = s_in*s_w * sum_k A[m,k]*Wt[n,k] + round(bias/sc)*sc ----
constexpr int BM = 128, BN = 128, BK = 32, LDP = 40;  // LDP: padded LDS row (16B aligned)

__global__ __launch_bounds__(256)
void gemm_kernel(const u16* __restrict__ A, const u16* __restrict__ Wt,
                 const float* __restrict__ bias, float* __restrict__ C,
                 const u32* __restrict__ slot_in, const u32* __restrict__ slot_w) {
  constexpr int K = NDM, N = NDM;
  __shared__ __align__(16) u16 As[BM][LDP];
  __shared__ __align__(16) u16 Bs[BN][LDP];
  const int tid = threadIdx.x;
  const int lane = tid & 63, wave = tid >> 6;
  const int wm = (wave & 1) * 64, wn = (wave >> 1) * 64;
  const int r16 = lane & 15, quad = lane >> 4;
  const int bm = blockIdx.x * BM, bn = blockIdx.y * BN;

  f32x4 acc[4][4] = {};

  for (int k0 = 0; k0 < K; k0 += BK) {
    __syncthreads();
#pragma unroll
    for (int c = 0; c < 2; c++) {
      int chunk = c * 256 + tid;          // 512 chunks of 8 bf16 per tile
      int r = chunk >> 2, kc = (chunk & 3) * 8;
      *(int4*)(&As[r][kc]) = *(const int4*)(A + (size_t)(bm + r) * K + (k0 + kc));
      *(int4*)(&Bs[r][kc]) = *(const int4*)(Wt + (size_t)(bn + r) * K + (k0 + kc));
    }
    __syncthreads();
    short8 af[4], bfr[4];
#pragma unroll
    for (int i = 0; i < 4; i++) af[i] = *(const short8*)(&As[wm + i * 16 + r16][quad * 8]);
#pragma unroll
    for (int j = 0; j < 4; j++) bfr[j] = *(const short8*)(&Bs[wn + j * 16 + r16][quad * 8]);
#pragma unroll
    for (int i = 0; i < 4; i++)
#pragma unroll
      for (int j = 0; j < 4; j++)
        acc[i][j] = __builtin_amdgcn_mfma_f32_16x16x32_bf16(af[i], bfr[j], acc[i][j], 0, 0, 0);
  }

  float s_in = fmaxf(fdec(*slot_in), QEPS) / 255.0f;
  float s_w  = fmaxf(fdec(*slot_w),  QEPS) / 127.0f;
  float sc = s_in * s_w;
#pragma unroll
  for (int j = 0; j < 4; j++) {
    int gc = bn + wn + j * 16 + r16;
    float bq = rintf(bias[gc] / sc) * sc;
#pragma unroll
    for (int i = 0; i < 4; i++) {
      int gr = bm + wm + i * 16 + quad * 4;
#pragma unroll
      for (int r = 0; r < 4; r++)
        C[(size_t)(gr + r) * N + gc] = acc[i][j][r] * sc + bq;
    }
  }
}

// per-seq-position absmax of proj_{q,k,v} (reduced over batch and all 1024 channels)
__global__ void rowscale_kernel(const float* __restrict__ pq, const float* __restrict__ pk,
                                const float* __restrict__ pv, float* __restrict__ scl) {
  const float* src = blockIdx.y == 0 ? pq : (blockIdx.y == 1 ? pk : pv);
  int s = blockIdx.x;
  float m = 0.0f;
  for (int idx = threadIdx.x; idx < NB * NDM; idx += 256) {
    int b = idx >> 10, o = idx & (NDM - 1);
    m = fmaxf(m, fabsf(src[((size_t)b * NS + s) * NDM + o]));
  }
  for (int off = 32; off; off >>= 1) m = fmaxf(m, __shfl_down(m, off));
  __shared__ float sm[4];
  if ((threadIdx.x & 63) == 0) sm[threadIdx.x >> 6] = m;
  __syncthreads();
  if (threadIdx.x == 0)
    scl[8 + blockIdx.y * 128 + s] = fmaxf(fmaxf(sm[0], sm[1]), fmaxf(sm[2], sm[3]));
}

// scores + online softmax; writes UNNORMALIZED exp to pexp, row sums to rs
__global__ __launch_bounds__(128)
void scores_kernel(const float* __restrict__ projq, const float* __restrict__ projk,
                   const int* __restrict__ mask, const float* __restrict__ scl,
                   float* __restrict__ pexp, float* __restrict__ rs) {
  const int bh = blockIdx.x, b = bh >> 4, h = bh & 15;
  const int i = threadIdx.x;  // row 0..127
  __shared__ u16 Ks[NS][NDK + 8];   // quantized ints as bf16 (exact)
  __shared__ float skv[NS];
  {
    float sk = fmaxf(scl[8 + 128 + i], QEPS) / 127.0f;
    skv[i] = sk;
    const float* krow = projk + ((size_t)b * NS + i) * NDM + h * NDK;
    for (int d = 0; d < NDK; d++)
      Ks[i][d] = f2bf(fminf(fmaxf(rintf(krow[d] / sk), -128.0f), 127.0f));
  }
  float qrow[NDK];
  {
    float sq_ = fmaxf(scl[8 + i], QEPS) / 127.0f;
    const float* qptr = projq + ((size_t)b * NS + i) * NDM + h * NDK;
#pragma unroll
    for (int d = 0; d < NDK; d++)
      qrow[d] = fminf(fmaxf(rintf(qptr[d] / sq_), -128.0f), 127.0f);
  }
  float sq = fmaxf(scl[8 + i], QEPS) / 127.0f;
  __syncthreads();

  const int* mrow = mask + ((size_t)b * NS + i) * NS;
  float mmax = -INFINITY;
  for (int j = 0; j < NS; j++) {
    float acc = 0.0f;
#pragma unroll
    for (int d = 0; d < NDK; d++) acc = fmaf(qrow[d], bf2f(Ks[j][d]), acc);
    float v = acc * (sq * skv[j]) * 0.125f;
    if (mrow[j] == 0) v = -1e9f;
    mmax = fmaxf(mmax, v);
  }
  float sum = 0.0f;
  float* prow = pexp + ((size_t)bh * NS + i) * NS;
  for (int j = 0; j < NS; j++) {
    float acc = 0.0f;
#pragma unroll
    for (int d = 0; d < NDK; d++) acc = fmaf(qrow[d], bf2f(Ks[j][d]), acc);
    float v = acc * (sq * skv[j]) * 0.125f;
    if (mrow[j] == 0) v = -1e9f;
    float e = expf(v - mmax);
    sum += e;
    prow[j] = e;
  }
  rs[(size_t)bh * NS + i] = sum;
}

// per-column (key position) max of normalized p_attn
__global__ void pcolmax_kernel(const float* __restrict__ pexp, const float* __restrict__ rs,
                               int* __restrict__ out) {
  __shared__ int sm[NS];
  int tid = threadIdx.x;  // 256
  if (tid < NS) sm[tid] = 0;
  __syncthreads();
  float m = 0.0f;
  const size_t total = (size_t)NB * NH * NS * NS;
  size_t stride = (size_t)gridDim.x * blockDim.x;  // multiple of 128 -> j fixed per thread
  for (size_t idx = (size_t)blockIdx.x * blockDim.x + tid; idx < total; idx += stride) {
    float inv = 1.0f / rs[idx >> 7];
    m = fmaxf(m, pexp[idx] * inv);
  }
  atomicMax(&sm[tid & 127], __float_as_int(m));  // p > 0: int compare ok
  __syncthreads();
  if (tid < NS) atomicMax(&out[tid], sm[tid]);
}

// x[b,i,h*64+d] = sum_j q(p)[i,j] * q(v)[j,d] * s_p[j]*s_v[j]; fused global max(x)
__global__ __launch_bounds__(128)
void pv_kernel(const float* __restrict__ pexp, const float* __restrict__ rs,
               const float* __restrict__ projv, const float* __restrict__ scl,
               float* __restrict__ xout, u32* __restrict__ xmax_slot) {
  const int bh = blockIdx.x, b = bh >> 4, h = bh & 15;
  const int i = threadIdx.x;
  __shared__ float Vc[NS][NDK + 1];
  __shared__ float spv[NS];
  {
    float sv = fmaxf(scl[8 + 256 + i], QEPS) / 127.0f;
    float sp = fmaxf(scl[8 + 384 + i], QEPS) / 127.0f;
    spv[i] = sp;
    const float* vrow = projv + ((size_t)b * NS + i) * NDM + h * NDK;
    float f = sv * sp;
    for (int d = 0; d < NDK; d++) {
      float vi = fminf(fmaxf(rintf(vrow[d] / sv), -128.0f), 127.0f);
      Vc[i][d] = vi * f;
    }
  }
  __syncthreads();
  float acc[NDK];
#pragma unroll
  for (int d = 0; d < NDK; d++) acc[d] = 0.0f;
  const float* prow = pexp + ((size_t)bh * NS + i) * NS;
  float inv = 1.0f / rs[(size_t)bh * NS + i];
  for (int j = 0; j < NS; j++) {
    float p = prow[j] * inv;
    float piq = fminf(fmaxf(rintf(p / spv[j]), -128.0f), 127.0f);
#pragma unroll
    for (int d = 0; d < NDK; d++) acc[d] = fmaf(piq, Vc[j][d], acc[d]);
  }
  float* xrow = xout + ((size_t)b * NS + i) * NDM + h * NDK;
  float mx = -INFINITY;
#pragma unroll
  for (int d = 0; d < NDK; d++) { xrow[d] = acc[d]; mx = fmaxf(mx, acc[d]); }
  for (int off = 32; off; off >>= 1) mx = fmaxf(mx, __shfl_down(mx, off));
  if ((threadIdx.x & 63) == 0) atomicMax(xmax_slot, fenc(mx));
}

// ---------------- workspace layout ----------------
constexpr size_t OFF_SCL  = 0;                                  // 8 KB
constexpr size_t W_BYTES  = (size_t)NDM * NDM * 2;              // 2 MB
constexpr size_t OFF_W    = 8 * 1024;
constexpr size_t OFF_XQ   = OFF_W + 4 * W_BYTES;                // bf16 8192x1024
constexpr size_t OFF_PQ   = OFF_XQ + (size_t)NM * NDM * 2;
constexpr size_t OFF_PK   = OFF_PQ + (size_t)NM * NDM * 4;
constexpr size_t OFF_PV   = OFF_PK + (size_t)NM * NDM * 4;
constexpr size_t OFF_PATT = OFF_PV + (size_t)NM * NDM * 4;      // B*H*S*S f32
constexpr size_t OFF_RS   = OFF_PATT + (size_t)NB * NH * NS * NS * 4;

extern "C" void kernel_launch(void* const* d_in, const int* in_sizes, int n_in,
                              void* d_out, int out_size, void* d_ws, size_t ws_size,
                              hipStream_t stream) {
  const float* query = (const float*)d_in[0];
  const float* key   = (const float*)d_in[1];
  const float* value = (const float*)d_in[2];
  const int*   mask  = (const int*)d_in[3];
  const float* Wq = (const float*)d_in[4];  const float* bq = (const float*)d_in[5];
  const float* Wk = (const float*)d_in[6];  const float* bk = (const float*)d_in[7];
  const float* Wv = (const float*)d_in[8];  const float* bv = (const float*)d_in[9];
  const float* Wo = (const float*)d_in[10]; const float* bo = (const float*)d_in[11];

  char* ws = (char*)d_ws;
  float* scl = (float*)(ws + OFF_SCL);
  u32*   sclu = (u32*)scl;
  u16* wqb = (u16*)(ws + OFF_W);
  u16* wkb = wqb + (size_t)NDM * NDM;
  u16* wvb = wkb + (size_t)NDM * NDM;
  u16* wob = wvb + (size_t)NDM * NDM;
  u16* xq = (u16*)(ws + OFF_XQ);
  float* projq = (float*)(ws + OFF_PQ);
  float* projk = (float*)(ws + OFF_PK);
  float* projv = (float*)(ws + OFF_PV);
  float* patt  = (float*)(ws + OFF_PATT);
  float* rsbuf = (float*)(ws + OFF_RS);
  float* xout  = projq;  // proj_q dead after scores_kernel

  const size_t nIn = (size_t)NM * NDM;     // 8.4M
  const size_t nW  = (size_t)NDM * NDM;    // 1M

  init_kernel<<<1, 256, 0, stream>>>(sclu);

  reduce_max_kernel<<<512, 256, 0, stream>>>(query, nIn, sclu + 0, 0);
  reduce_max_kernel<<<512, 256, 0, stream>>>(key,   nIn, sclu + 1, 0);
  reduce_max_kernel<<<512, 256, 0, stream>>>(value, nIn, sclu + 2, 0);
  reduce_max_kernel<<<256, 256, 0, stream>>>(Wq, nW, sclu + 3, 1);
  reduce_max_kernel<<<256, 256, 0, stream>>>(Wk, nW, sclu + 4, 1);
  reduce_max_kernel<<<256, 256, 0, stream>>>(Wv, nW, sclu + 5, 1);
  reduce_max_kernel<<<256, 256, 0, stream>>>(Wo, nW, sclu + 6, 1);

  quant_w_kernel<<<512, 256, 0, stream>>>(Wq, wqb, nW, sclu + 3);
  quant_w_kernel<<<512, 256, 0, stream>>>(Wk, wkb, nW, sclu + 4);
  quant_w_kernel<<<512, 256, 0, stream>>>(Wv, wvb, nW, sclu + 5);
  quant_w_kernel<<<512, 256, 0, stream>>>(Wo, wob, nW, sclu + 6);

  dim3 gg(NM / BM, NDM / BN);
  quant_u8_kernel<<<2048, 256, 0, stream>>>(query, xq, nIn, sclu + 0);
  gemm_kernel<<<gg, 256, 0, stream>>>(xq, wqb, bq, projq, sclu + 0, sclu + 3);
  quant_u8_kernel<<<2048, 256, 0, stream>>>(key, xq, nIn, sclu + 1);
  gemm_kernel<<<gg, 256, 0, stream>>>(xq, wkb, bk, projk, sclu + 1, sclu + 4);
  quant_u8_kernel<<<2048, 256, 0, stream>>>(value, xq, nIn, sclu + 2);
  gemm_kernel<<<gg, 256, 0, stream>>>(xq, wvb, bv, projv, sclu + 2, sclu + 5);

  rowscale_kernel<<<dim3(128, 3), 256, 0, stream>>>(projq, projk, projv, scl);

  scores_kernel<<<NB * NH, 128, 0, stream>>>(projq, projk, mask, scl, patt, rsbuf);
  pcolmax_kernel<<<512, 256, 0, stream>>>(patt, rsbuf, (int*)(sclu + 392));
  pv_kernel<<<NB * NH, 128, 0, stream>>>(patt, rsbuf, projv, scl, xout, sclu + 7);

  quant_u8_kernel<<<2048, 256, 0, stream>>>(xout, xq, nIn, sclu + 7);
  gemm_kernel<<<gg, 256, 0, stream>>>(xq, wob, bo, (float*)d_out, sclu + 7, sclu + 6);
}

// Round 2
// 653.146 us; speedup vs baseline: 1.4192x; 1.4192x over previous
//
#include <hip/hip_runtime.h>
#include <hip/hip_bf16.h>
#include <math.h>

typedef unsigned short u16;
typedef unsigned int u32;
typedef unsigned char u8;

constexpr int NB = 64, NS = 128, NDM = 1024, NH = 16, NDK = 64;
constexpr int NM = NB * NS;           // 8192 rows (B*S)
constexpr float QEPS = 1e-8f;

typedef __attribute__((ext_vector_type(8))) short short8;
typedef __attribute__((ext_vector_type(4))) float f32x4;

// ---- ordered-uint encoding so atomicMax(u32) == float max (handles negatives) ----
__device__ __forceinline__ u32 fenc(float f) {
  u32 u = __float_as_uint(f);
  return (u & 0x80000000u) ? ~u : (u | 0x80000000u);
}
__device__ __forceinline__ float fdec(u32 u) {
  u = (u & 0x80000000u) ? (u & 0x7FFFFFFFu) : ~u;
  return __uint_as_float(u);
}
// quantized values are small integers -> low mantissa bits zero -> exact truncation
__device__ __forceinline__ u16 f2bf(float f) { return (u16)(__float_as_uint(f) >> 16); }
__device__ __forceinline__ float bf2f(u16 u) { return __uint_as_float(((u32)u) << 16); }

// ---------------- scale-slot layout (floats at ws offset 0) ----------------
// [0] enc max(query) [1] enc max(key) [2] enc max(value)
// [3..6] enc absmax(Wq,Wk,Wv,Wo)  [7] enc max(x_attnout)
// [8..135]   absmax_q per s   [136..263] absmax_k per s
// [264..391] absmax_v per s   [392..519] max_p per j (plain float bits, p>0)

__global__ void init_kernel(u32* scl) {
  for (int i = threadIdx.x; i < 2048; i += blockDim.x) scl[i] = 0u;
}

__global__ void reduce_max_kernel(const float* __restrict__ src, size_t n,
                                  u32* __restrict__ slot, int useAbs) {
  float m = -INFINITY;
  size_t stride = (size_t)gridDim.x * blockDim.x;
  for (size_t i = (size_t)blockIdx.x * blockDim.x + threadIdx.x; i < n; i += stride) {
    float v = src[i];
    if (useAbs) v = fabsf(v);
    m = fmaxf(m, v);
  }
  for (int off = 32; off; off >>= 1) m = fmaxf(m, __shfl_down(m, off));
  __shared__ float sm[8];
  int lane = threadIdx.x & 63, wid = threadIdx.x >> 6;
  if (lane == 0) sm[wid] = m;
  __syncthreads();
  if (threadIdx.x == 0) {
    float r = sm[0];
    for (int i = 1; i < (int)(blockDim.x >> 6); i++) r = fmaxf(r, sm[i]);
    atomicMax(slot, fenc(r));
  }
}

__global__ void quant_u8_kernel(const float* __restrict__ src, u16* __restrict__ dst,
                                size_t n, const u32* __restrict__ slot) {
  float s = fmaxf(fdec(*slot), QEPS) / 255.0f;
  size_t stride = (size_t)gridDim.x * blockDim.x;
  for (size_t i = (size_t)blockIdx.x * blockDim.x + threadIdx.x; i < n; i += stride) {
    float q = fminf(fmaxf(rintf(src[i] / s), 0.0f), 255.0f);
    dst[i] = f2bf(q);
  }
}

__global__ void quant_w_kernel(const float* __restrict__ src, u16* __restrict__ dst,
                               size_t n, const u32* __restrict__ slot) {
  float s = fmaxf(fdec(*slot), QEPS) / 127.0f;
  size_t stride = (size_t)gridDim.x * blockDim.x;
  for (size_t i = (size_t)blockIdx.x * blockDim.x + threadIdx.x; i < n; i += stride) {
    float q = fminf(fmaxf(rintf(src[i] / s), -127.0f), 127.0f);
    dst[i] = f2bf(q);
  }
}

// ---------------- GEMM (unchanged from R1) ----------------
constexpr int BM = 128, BN = 128, BK = 32, LDP = 40;

__global__ __launch_bounds__(256)
void gemm_kernel(const u16* __restrict__ A, const u16* __restrict__ Wt,
                 const float* __restrict__ bias, float* __restrict__ C,
                 const u32* __restrict__ slot_in, const u32* __restrict__ slot_w) {
  constexpr int K = NDM, N = NDM;
  __shared__ __align__(16) u16 As[BM][LDP];
  __shared__ __align__(16) u16 Bs[BN][LDP];
  const int tid = threadIdx.x;
  const int lane = tid & 63, wave = tid >> 6;
  const int wm = (wave & 1) * 64, wn = (wave >> 1) * 64;
  const int r16 = lane & 15, quad = lane >> 4;
  const int bm = blockIdx.x * BM, bn = blockIdx.y * BN;

  f32x4 acc[4][4] = {};

  for (int k0 = 0; k0 < K; k0 += BK) {
    __syncthreads();
#pragma unroll
    for (int c = 0; c < 2; c++) {
      int chunk = c * 256 + tid;
      int r = chunk >> 2, kc = (chunk & 3) * 8;
      *(int4*)(&As[r][kc]) = *(const int4*)(A + (size_t)(bm + r) * K + (k0 + kc));
      *(int4*)(&Bs[r][kc]) = *(const int4*)(Wt + (size_t)(bn + r) * K + (k0 + kc));
    }
    __syncthreads();
    short8 af[4], bfr[4];
#pragma unroll
    for (int i = 0; i < 4; i++) af[i] = *(const short8*)(&As[wm + i * 16 + r16][quad * 8]);
#pragma unroll
    for (int j = 0; j < 4; j++) bfr[j] = *(const short8*)(&Bs[wn + j * 16 + r16][quad * 8]);
#pragma unroll
    for (int i = 0; i < 4; i++)
#pragma unroll
      for (int j = 0; j < 4; j++)
        acc[i][j] = __builtin_amdgcn_mfma_f32_16x16x32_bf16(af[i], bfr[j], acc[i][j], 0, 0, 0);
  }

  float s_in = fmaxf(fdec(*slot_in), QEPS) / 255.0f;
  float s_w  = fmaxf(fdec(*slot_w),  QEPS) / 127.0f;
  float sc = s_in * s_w;
#pragma unroll
  for (int j = 0; j < 4; j++) {
    int gc = bn + wn + j * 16 + r16;
    float bq = rintf(bias[gc] / sc) * sc;
#pragma unroll
    for (int i = 0; i < 4; i++) {
      int gr = bm + wm + i * 16 + quad * 4;
#pragma unroll
      for (int r = 0; r < 4; r++)
        C[(size_t)(gr + r) * N + gc] = acc[i][j][r] * sc + bq;
    }
  }
}

// per-seq-position absmax of proj_{q,k,v}
__global__ void rowscale_kernel(const float* __restrict__ pq, const float* __restrict__ pk,
                                const float* __restrict__ pv, float* __restrict__ scl) {
  const float* src = blockIdx.y == 0 ? pq : (blockIdx.y == 1 ? pk : pv);
  int s = blockIdx.x;
  float m = 0.0f;
  for (int idx = threadIdx.x; idx < NB * NDM; idx += 256) {
    int b = idx >> 10, o = idx & (NDM - 1);
    m = fmaxf(m, fabsf(src[((size_t)b * NS + s) * NDM + o]));
  }
  for (int off = 32; off; off >>= 1) m = fmaxf(m, __shfl_down(m, off));
  __shared__ float sm[4];
  if ((threadIdx.x & 63) == 0) sm[threadIdx.x >> 6] = m;
  __syncthreads();
  if (threadIdx.x == 0)
    scl[8 + blockIdx.y * 128 + s] = fmaxf(fmaxf(sm[0], sm[1]), fmaxf(sm[2], sm[3]));
}

// ---------------- attention helpers ----------------
constexpr int LQK = 72;  // padded LDS row for Q/K tiles (shorts)

// quantize one 32-float half-row of q and k into LDS (exact bf16 ints)
__device__ __forceinline__ void stage_qk(const float* __restrict__ projq,
                                         const float* __restrict__ projk,
                                         const float* __restrict__ scl,
                                         int b, int h, int tid,
                                         u16 (*Qs)[LQK], u16 (*Ks)[LQK],
                                         float* sqv, float* skv) {
  int row = tid >> 1, half = (tid & 1) * 32;
  float sq = fmaxf(scl[8 + row], QEPS) / 127.0f;
  float sk = fmaxf(scl[8 + 128 + row], QEPS) / 127.0f;
  if (half == 0) { sqv[row] = sq; skv[row] = sk; }
  const float* qp = projq + ((size_t)b * NS + row) * NDM + h * NDK + half;
  const float* kp = projk + ((size_t)b * NS + row) * NDM + h * NDK + half;
#pragma unroll
  for (int c = 0; c < 4; c++) {
    float4 q0 = *(const float4*)(qp + c * 8);
    float4 q1 = *(const float4*)(qp + c * 8 + 4);
    float4 k0 = *(const float4*)(kp + c * 8);
    float4 k1 = *(const float4*)(kp + c * 8 + 4);
    short8 vq, vk;
    vq[0] = f2bf(fminf(fmaxf(rintf(q0.x / sq), -128.f), 127.f));
    vq[1] = f2bf(fminf(fmaxf(rintf(q0.y / sq), -128.f), 127.f));
    vq[2] = f2bf(fminf(fmaxf(rintf(q0.z / sq), -128.f), 127.f));
    vq[3] = f2bf(fminf(fmaxf(rintf(q0.w / sq), -128.f), 127.f));
    vq[4] = f2bf(fminf(fmaxf(rintf(q1.x / sq), -128.f), 127.f));
    vq[5] = f2bf(fminf(fmaxf(rintf(q1.y / sq), -128.f), 127.f));
    vq[6] = f2bf(fminf(fmaxf(rintf(q1.z / sq), -128.f), 127.f));
    vq[7] = f2bf(fminf(fmaxf(rintf(q1.w / sq), -128.f), 127.f));
    vk[0] = f2bf(fminf(fmaxf(rintf(k0.x / sk), -128.f), 127.f));
    vk[1] = f2bf(fminf(fmaxf(rintf(k0.y / sk), -128.f), 127.f));
    vk[2] = f2bf(fminf(fmaxf(rintf(k0.z / sk), -128.f), 127.f));
    vk[3] = f2bf(fminf(fmaxf(rintf(k0.w / sk), -128.f), 127.f));
    vk[4] = f2bf(fminf(fmaxf(rintf(k1.x / sk), -128.f), 127.f));
    vk[5] = f2bf(fminf(fmaxf(rintf(k1.y / sk), -128.f), 127.f));
    vk[6] = f2bf(fminf(fmaxf(rintf(k1.z / sk), -128.f), 127.f));
    vk[7] = f2bf(fminf(fmaxf(rintf(k1.w / sk), -128.f), 127.f));
    *(short8*)&Qs[row][half + c * 8] = vq;
    *(short8*)&Ks[row][half + c * 8] = vk;
  }
}

// QK^T via MFMA + masked softmax; acc holds normalized p on exit.
// wave handles rows [wave*32, wave*32+32); cols 0..127 across 8 n-tiles.
__device__ __forceinline__ void compute_p(int b, const int* __restrict__ mask,
                                          int wave, int lane,
                                          const u16 (*Qs)[LQK], const u16 (*Ks)[LQK],
                                          const float* sqv, const float* skv,
                                          f32x4 acc[2][8]) {
  const int r16 = lane & 15, quad = lane >> 4;
  const int rowbase = wave * 32;
#pragma unroll
  for (int kk = 0; kk < 2; kk++) {
    short8 af[2];
#pragma unroll
    for (int m = 0; m < 2; m++)
      af[m] = *(const short8*)&Qs[rowbase + m * 16 + r16][kk * 32 + quad * 8];
#pragma unroll
    for (int n = 0; n < 8; n++) {
      short8 bv = *(const short8*)&Ks[n * 16 + r16][kk * 32 + quad * 8];
#pragma unroll
      for (int m = 0; m < 2; m++)
        acc[m][n] = __builtin_amdgcn_mfma_f32_16x16x32_bf16(af[m], bv, acc[m][n], 0, 0, 0);
    }
  }
  float skc[8];
#pragma unroll
  for (int n = 0; n < 8; n++) skc[n] = skv[n * 16 + r16];
#pragma unroll
  for (int m = 0; m < 2; m++) {
#pragma unroll
    for (int r = 0; r < 4; r++) {
      int row = rowbase + m * 16 + quad * 4 + r;
      float sq = sqv[row];
      const int* mrow = mask + ((size_t)b * NS + row) * NS;
      float vals[8];
      float mx = -INFINITY;
#pragma unroll
      for (int n = 0; n < 8; n++) {
        float v = acc[m][n][r] * (sq * skc[n]) * 0.125f;
        if (mrow[n * 16 + r16] == 0) v = -1e9f;
        vals[n] = v;
        mx = fmaxf(mx, v);
      }
#pragma unroll
      for (int off = 1; off < 16; off <<= 1) mx = fmaxf(mx, __shfl_xor(mx, off));
      float sum = 0.0f;
#pragma unroll
      for (int n = 0; n < 8; n++) { vals[n] = __expf(vals[n] - mx); sum += vals[n]; }
#pragma unroll
      for (int off = 1; off < 16; off <<= 1) sum += __shfl_xor(sum, off);
      float inv = 1.0f / sum;
#pragma unroll
      for (int n = 0; n < 8; n++) acc[m][n][r] = vals[n] * inv;
    }
  }
}

// Kernel A: scores + softmax + global per-column max of p (no p written!)
__global__ __launch_bounds__(256)
void attn_scores_kernel(const float* __restrict__ projq, const float* __restrict__ projk,
                        const int* __restrict__ mask, const float* __restrict__ scl,
                        u32* __restrict__ sclu) {
  const int bh = blockIdx.x, b = bh >> 4, h = bh & 15;
  const int tid = threadIdx.x, lane = tid & 63, wave = tid >> 6;
  const int r16 = lane & 15, quad = lane >> 4;
  __shared__ __align__(16) u16 Qs[NS][LQK];
  __shared__ __align__(16) u16 Ks[NS][LQK];
  __shared__ float sqv[NS], skv[NS];
  __shared__ float cmw[4][NS];

  stage_qk(projq, projk, scl, b, h, tid, Qs, Ks, sqv, skv);
  __syncthreads();

  f32x4 acc[2][8] = {};
  compute_p(b, mask, wave, lane, Qs, Ks, sqv, skv, acc);

#pragma unroll
  for (int n = 0; n < 8; n++) {
    float c = -INFINITY;
#pragma unroll
    for (int m = 0; m < 2; m++)
#pragma unroll
      for (int r = 0; r < 4; r++) c = fmaxf(c, acc[m][n][r]);
    c = fmaxf(c, __shfl_xor(c, 16));
    c = fmaxf(c, __shfl_xor(c, 32));
    if (quad == 0) cmw[wave][n * 16 + r16] = c;
  }
  __syncthreads();
  if (tid < NS) {
    float c = fmaxf(fmaxf(cmw[0][tid], cmw[1][tid]), fmaxf(cmw[2][tid], cmw[3][tid]));
    atomicMax((int*)&sclu[392 + tid], __float_as_int(c));  // p > 0: int compare ok
  }
}

// Kernel B: recompute p, quantize (colmax scales), PV via MFMA with split-precision V
constexpr int LPV = 136;  // padded row: Ps bytes / V shorts

__global__ __launch_bounds__(256)
void attn_pv_kernel(const float* __restrict__ projq, const float* __restrict__ projk,
                    const float* __restrict__ projv, const int* __restrict__ mask,
                    const float* __restrict__ scl, float* __restrict__ xout,
                    u32* __restrict__ xmax_slot) {
  const int bh = blockIdx.x, b = bh >> 4, h = bh & 15;
  const int tid = threadIdx.x, lane = tid & 63, wave = tid >> 6;
  const int r16 = lane & 15, quad = lane >> 4;

  __shared__ __align__(16) char smem[53248];
  u16 (*Qs)[LQK] = (u16(*)[LQK])smem;                       // [0, 18432)
  u16 (*Ks)[LQK] = (u16(*)[LQK])(smem + 18432);             // [18432, 36864)
  u8  (*Ps)[LPV] = (u8(*)[LPV])smem;                        // [0, 17408)   (aliases Qs)
  u16 (*Vhi)[LPV] = (u16(*)[LPV])(smem + 18432);            // [18432, 35840)
  u16 (*Vlo)[LPV] = (u16(*)[LPV])(smem + 18432 + 17408);    // [35840, 53248)
  __shared__ float sqv[NS], skv[NS];

  stage_qk(projq, projk, scl, b, h, tid, Qs, Ks, sqv, skv);
  __syncthreads();

  f32x4 acc[2][8] = {};
  compute_p(b, mask, wave, lane, Qs, Ks, sqv, skv, acc);
  __syncthreads();  // all Qs/Ks reads complete; regions reused below

  // quantize p -> int8 in LDS (A-operand layout source: row-major [i][j])
  const int rowbase = wave * 32;
  float spc[8];
#pragma unroll
  for (int n = 0; n < 8; n++) spc[n] = fmaxf(scl[392 + n * 16 + r16], QEPS) / 127.0f;
#pragma unroll
  for (int m = 0; m < 2; m++)
#pragma unroll
    for (int r = 0; r < 4; r++) {
      int row = rowbase + m * 16 + quad * 4 + r;
#pragma unroll
      for (int n = 0; n < 8; n++) {
        float pq = fminf(fmaxf(rintf(acc[m][n][r] / spc[n]), -128.f), 127.f);
        Ps[row][n * 16 + r16] = (u8)(int)pq;
      }
    }

  // load V, quantize, fold per-j scale (contraction axis) via hi/lo bf16 split,
  // store transposed [d][j] for contiguous B-fragment reads
  {
    int j = tid >> 1, half = (tid & 1) * 32;
    float sv = fmaxf(scl[8 + 256 + j], QEPS) / 127.0f;
    float sp = fmaxf(scl[392 + j], QEPS) / 127.0f;
    float g = sv * sp;
    const float* vp = projv + ((size_t)b * NS + j) * NDM + h * NDK + half;
#pragma unroll
    for (int d = 0; d < 32; d++) {
      float vq = fminf(fmaxf(rintf(vp[d] / sv), -128.f), 127.f);
      float w = vq * g;
      u16 hi = f2bf(w);
      float lo = w - bf2f(hi);
      Vhi[half + d][j] = hi;
      Vlo[half + d][j] = f2bf(lo);
    }
  }
  __syncthreads();

  // x = P V : rows 32/wave, 64 cols (4 n-tiles), K=128 (4 k-steps)
  f32x4 xacc[2][4] = {};
#pragma unroll
  for (int kk = 0; kk < 4; kk++) {
    short8 pa[2];
#pragma unroll
    for (int m = 0; m < 2; m++) {
      const u8* src = &Ps[rowbase + m * 16 + r16][kk * 32 + quad * 8];
      uint2 wv = *(const uint2*)src;
#pragma unroll
      for (int t = 0; t < 4; t++) pa[m][t] = (short)f2bf((float)((wv.x >> (8 * t)) & 255u));
#pragma unroll
      for (int t = 0; t < 4; t++) pa[m][4 + t] = (short)f2bf((float)((wv.y >> (8 * t)) & 255u));
    }
#pragma unroll
    for (int n = 0; n < 4; n++) {
      short8 vh = *(const short8*)&Vhi[n * 16 + r16][kk * 32 + quad * 8];
      short8 vl = *(const short8*)&Vlo[n * 16 + r16][kk * 32 + quad * 8];
#pragma unroll
      for (int m = 0; m < 2; m++) {
        xacc[m][n] = __builtin_amdgcn_mfma_f32_16x16x32_bf16(pa[m], vh, xacc[m][n], 0, 0, 0);
        xacc[m][n] = __builtin_amdgcn_mfma_f32_16x16x32_bf16(pa[m], vl, xacc[m][n], 0, 0, 0);
      }
    }
  }

  float mx = -INFINITY;
#pragma unroll
  for (int m = 0; m < 2; m++)
#pragma unroll
    for (int n = 0; n < 4; n++) {
#pragma unroll
      for (int r = 0; r < 4; r++) {
        int row = rowbase + m * 16 + quad * 4 + r;
        xout[((size_t)b * NS + row) * NDM + h * NDK + n * 16 + r16] = xacc[m][n][r];
        mx = fmaxf(mx, xacc[m][n][r]);
      }
    }
#pragma unroll
  for (int off = 1; off < 64; off <<= 1) mx = fmaxf(mx, __shfl_xor(mx, off));
  if (lane == 0) atomicMax(xmax_slot, fenc(mx));
}

// ---------------- workspace layout ----------------
constexpr size_t OFF_SCL  = 0;
constexpr size_t W_BYTES  = (size_t)NDM * NDM * 2;
constexpr size_t OFF_W    = 8 * 1024;
constexpr size_t OFF_XQ   = OFF_W + 4 * W_BYTES;
constexpr size_t OFF_PQ   = OFF_XQ + (size_t)NM * NDM * 2;
constexpr size_t OFF_PK   = OFF_PQ + (size_t)NM * NDM * 4;
constexpr size_t OFF_PV   = OFF_PK + (size_t)NM * NDM * 4;

extern "C" void kernel_launch(void* const* d_in, const int* in_sizes, int n_in,
                              void* d_out, int out_size, void* d_ws, size_t ws_size,
                              hipStream_t stream) {
  const float* query = (const float*)d_in[0];
  const float* key   = (const float*)d_in[1];
  const float* value = (const float*)d_in[2];
  const int*   mask  = (const int*)d_in[3];
  const float* Wq = (const float*)d_in[4];  const float* bq = (const float*)d_in[5];
  const float* Wk = (const float*)d_in[6];  const float* bk = (const float*)d_in[7];
  const float* Wv = (const float*)d_in[8];  const float* bv = (const float*)d_in[9];
  const float* Wo = (const float*)d_in[10]; const float* bo = (const float*)d_in[11];

  char* ws = (char*)d_ws;
  float* scl = (float*)(ws + OFF_SCL);
  u32*   sclu = (u32*)scl;
  u16* wqb = (u16*)(ws + OFF_W);
  u16* wkb = wqb + (size_t)NDM * NDM;
  u16* wvb = wkb + (size_t)NDM * NDM;
  u16* wob = wvb + (size_t)NDM * NDM;
  u16* xq = (u16*)(ws + OFF_XQ);
  float* projq = (float*)(ws + OFF_PQ);
  float* projk = (float*)(ws + OFF_PK);
  float* projv = (float*)(ws + OFF_PV);
  float* xout  = projq;  // block-private region reuse: (b,h) reads == (b,h) writes

  const size_t nIn = (size_t)NM * NDM;
  const size_t nW  = (size_t)NDM * NDM;

  init_kernel<<<1, 256, 0, stream>>>(sclu);

  reduce_max_kernel<<<512, 256, 0, stream>>>(query, nIn, sclu + 0, 0);
  reduce_max_kernel<<<512, 256, 0, stream>>>(key,   nIn, sclu + 1, 0);
  reduce_max_kernel<<<512, 256, 0, stream>>>(value, nIn, sclu + 2, 0);
  reduce_max_kernel<<<256, 256, 0, stream>>>(Wq, nW, sclu + 3, 1);
  reduce_max_kernel<<<256, 256, 0, stream>>>(Wk, nW, sclu + 4, 1);
  reduce_max_kernel<<<256, 256, 0, stream>>>(Wv, nW, sclu + 5, 1);
  reduce_max_kernel<<<256, 256, 0, stream>>>(Wo, nW, sclu + 6, 1);

  quant_w_kernel<<<512, 256, 0, stream>>>(Wq, wqb, nW, sclu + 3);
  quant_w_kernel<<<512, 256, 0, stream>>>(Wk, wkb, nW, sclu + 4);
  quant_w_kernel<<<512, 256, 0, stream>>>(Wv, wvb, nW, sclu + 5);
  quant_w_kernel<<<512, 256, 0, stream>>>(Wo, wob, nW, sclu + 6);

  dim3 gg(NM / BM, NDM / BN);
  quant_u8_kernel<<<2048, 256, 0, stream>>>(query, xq, nIn, sclu + 0);
  gemm_kernel<<<gg, 256, 0, stream>>>(xq, wqb, bq, projq, sclu + 0, sclu + 3);
  quant_u8_kernel<<<2048, 256, 0, stream>>>(key, xq, nIn, sclu + 1);
  gemm_kernel<<<gg, 256, 0, stream>>>(xq, wkb, bk, projk, sclu + 1, sclu + 4);
  quant_u8_kernel<<<2048, 256, 0, stream>>>(value, xq, nIn, sclu + 2);
  gemm_kernel<<<gg, 256, 0, stream>>>(xq, wvb, bv, projv, sclu + 2, sclu + 5);

  rowscale_kernel<<<dim3(128, 3), 256, 0, stream>>>(projq, projk, projv, scl);

  attn_scores_kernel<<<NB * NH, 256, 0, stream>>>(projq, projk, mask, scl, sclu);
  attn_pv_kernel<<<NB * NH, 256, 0, stream>>>(projq, projk, projv, mask, scl, xout,
                                              sclu + 7);

  quant_u8_kernel<<<2048, 256, 0, stream>>>(xout, xq, nIn, sclu + 7);
  gemm_kernel<<<gg, 256, 0, stream>>>(xq, wob, bo, (float*)d_out, sclu + 7, sclu + 6);
}

// Round 3
// 474.751 us; speedup vs baseline: 1.9525x; 1.3758x over previous
//
#include <hip/hip_runtime.h>
#include <hip/hip_bf16.h>
#include <math.h>

typedef unsigned short u16;
typedef unsigned int u32;
typedef unsigned long long u64;
typedef signed char i8;

constexpr int NB = 64, NS = 128, NDM = 1024, NH = 16, NDK = 64;
constexpr int NM = NB * NS;  // 8192
constexpr float QEPS = 1e-8f;

typedef __attribute__((ext_vector_type(8))) short short8;
typedef __attribute__((ext_vector_type(4))) float f32x4;
typedef __attribute__((ext_vector_type(4))) int i32x4;

__device__ __forceinline__ u32 fenc(float f) {
  u32 u = __float_as_uint(f);
  return (u & 0x80000000u) ? ~u : (u | 0x80000000u);
}
__device__ __forceinline__ float fdec(u32 u) {
  u = (u & 0x80000000u) ? (u & 0x7FFFFFFFu) : ~u;
  return __uint_as_float(u);
}
// quantized values are small integers -> exact bf16 truncation
__device__ __forceinline__ u16 f2bf(float f) { return (u16)(__float_as_uint(f) >> 16); }
__device__ __forceinline__ float bf2f(u16 u) { return __uint_as_float(((u32)u) << 16); }

// async global->LDS, 16B per lane; lds base must be wave-uniform (dest = base + lane*16)
__device__ __forceinline__ void glds16(const void* g, void* l) {
  __builtin_amdgcn_global_load_lds(
      (const __attribute__((address_space(1))) void*)(unsigned long long)(uintptr_t)g,
      (__attribute__((address_space(3))) void*)(u32)(uintptr_t)l, 16, 0, 0);
}

// ---- scale slots (u32/float at ws offset 0) ----
// [0..2] enc max(q,k,v)  [3..6] enc absmax(W*)  [7] enc max(x)
// [8..135] absmax_q per s; [136..263] absmax_k; [264..391] absmax_v (plain float bits)
// [392..519] colmax_p per j (plain float bits)

__global__ void init_kernel(u32* scl) {
  for (int i = threadIdx.x; i < 2048; i += blockDim.x) scl[i] = 0u;
}

// mask[B,S,S] int32 -> bitmask [B*S][2] u64
__global__ void maskbits_kernel(const int* __restrict__ mask, u64* __restrict__ mb) {
  int row = blockIdx.x * 4 + (threadIdx.x >> 6);
  int lane = threadIdx.x & 63;
  const int* mrow = mask + (size_t)row * NS;
  u64 b0 = __ballot(mrow[lane] != 0);
  u64 b1 = __ballot(mrow[64 + lane] != 0);
  if (lane == 0) { mb[row * 2] = b0; mb[row * 2 + 1] = b1; }
}

// fused 7-way max reduce: y=0..2 max(q,k,v); y=3..6 absmax(Wq..Wo)
__global__ void fused_max_kernel(const float* __restrict__ q, const float* __restrict__ k,
                                 const float* __restrict__ v, const float* __restrict__ w0,
                                 const float* __restrict__ w1, const float* __restrict__ w2,
                                 const float* __restrict__ w3, u32* __restrict__ sclu) {
  int y = blockIdx.y;
  const float* src; size_t n4; int ab;
  switch (y) {
    case 0: src = q; n4 = (size_t)NM * NDM / 4; ab = 0; break;
    case 1: src = k; n4 = (size_t)NM * NDM / 4; ab = 0; break;
    case 2: src = v; n4 = (size_t)NM * NDM / 4; ab = 0; break;
    case 3: src = w0; n4 = (size_t)NDM * NDM / 4; ab = 1; break;
    case 4: src = w1; n4 = (size_t)NDM * NDM / 4; ab = 1; break;
    case 5: src = w2; n4 = (size_t)NDM * NDM / 4; ab = 1; break;
    default: src = w3; n4 = (size_t)NDM * NDM / 4; ab = 1; break;
  }
  float m = -INFINITY;
  size_t stride = (size_t)gridDim.x * blockDim.x;
  for (size_t i = (size_t)blockIdx.x * blockDim.x + threadIdx.x; i < n4; i += stride) {
    float4 f = ((const float4*)src)[i];
    if (ab) { f.x = fabsf(f.x); f.y = fabsf(f.y); f.z = fabsf(f.z); f.w = fabsf(f.w); }
    m = fmaxf(m, fmaxf(fmaxf(f.x, f.y), fmaxf(f.z, f.w)));
  }
  for (int off = 32; off; off >>= 1) m = fmaxf(m, __shfl_down(m, off));
  __shared__ float sm[4];
  if ((threadIdx.x & 63) == 0) sm[threadIdx.x >> 6] = m;
  __syncthreads();
  if (threadIdx.x == 0) {
    float r = fmaxf(fmaxf(sm[0], sm[1]), fmaxf(sm[2], sm[3]));
    atomicMax(&sclu[y], fenc(r));
  }
}

// fused weight quant: y=0..3, Wq..Wo -> bf16 int grid (-127..127)
__global__ void quant_w_kernel(const float* __restrict__ w0, const float* __restrict__ w1,
                               const float* __restrict__ w2, const float* __restrict__ w3,
                               u16* __restrict__ dst, const u32* __restrict__ sclu) {
  int y = blockIdx.y;
  const float* src = y == 0 ? w0 : y == 1 ? w1 : y == 2 ? w2 : w3;
  u16* d = dst + (size_t)y * NDM * NDM;
  float s = fmaxf(fdec(sclu[3 + y]), QEPS) / 127.0f;
  size_t n4 = (size_t)NDM * NDM / 4;
  size_t stride = (size_t)gridDim.x * blockDim.x;
  for (size_t i = (size_t)blockIdx.x * blockDim.x + threadIdx.x; i < n4; i += stride) {
    float4 f = ((const float4*)src)[i];
    ushort4 o;
    o.x = f2bf(fminf(fmaxf(rintf(f.x / s), -127.f), 127.f));
    o.y = f2bf(fminf(fmaxf(rintf(f.y / s), -127.f), 127.f));
    o.z = f2bf(fminf(fmaxf(rintf(f.z / s), -127.f), 127.f));
    o.w = f2bf(fminf(fmaxf(rintf(f.w / s), -127.f), 127.f));
    ((ushort4*)d)[i] = o;
  }
}

// uint8 activation fake-quant -> bf16 integer grid (0..255)
__global__ void quant_u8_kernel(const float* __restrict__ src, u16* __restrict__ dst,
                                const u32* __restrict__ slot) {
  float s = fmaxf(fdec(*slot), QEPS) / 255.0f;
  size_t n4 = (size_t)NM * NDM / 4;
  size_t stride = (size_t)gridDim.x * blockDim.x;
  for (size_t i = (size_t)blockIdx.x * blockDim.x + threadIdx.x; i < n4; i += stride) {
    float4 f = ((const float4*)src)[i];
    ushort4 o;
    o.x = f2bf(fminf(fmaxf(rintf(f.x / s), 0.f), 255.f));
    o.y = f2bf(fminf(fmaxf(rintf(f.y / s), 0.f), 255.f));
    o.z = f2bf(fminf(fmaxf(rintf(f.z / s), 0.f), 255.f));
    o.w = f2bf(fminf(fmaxf(rintf(f.w / s), 0.f), 255.f));
    ((ushort4*)dst)[i] = o;
  }
}

// proj fp32 -> int8 with per-s scale; y=0..2 selects q/k/v
__global__ void qkv_i8_kernel(const float* __restrict__ projbase, i8* __restrict__ dstbase,
                              const float* __restrict__ scl) {
  int y = blockIdx.y;
  const float* src = projbase + (size_t)y * NM * NDM;
  i8* dst = dstbase + (size_t)y * NM * NDM;
  const float* sb = scl + 8 + y * 128;
  size_t n4 = (size_t)NM * NDM / 4;
  size_t stride = (size_t)gridDim.x * blockDim.x;
  for (size_t i = (size_t)blockIdx.x * blockDim.x + threadIdx.x; i < n4; i += stride) {
    int s_idx = (int)((i >> 8) & 127);  // (4*i)>>10 & 127
    float s = fmaxf(sb[s_idx], QEPS) / 127.0f;
    float4 f = ((const float4*)src)[i];
    int a = (int)fminf(fmaxf(rintf(f.x / s), -128.f), 127.f);
    int b = (int)fminf(fmaxf(rintf(f.y / s), -128.f), 127.f);
    int c = (int)fminf(fmaxf(rintf(f.z / s), -128.f), 127.f);
    int d = (int)fminf(fmaxf(rintf(f.w / s), -128.f), 127.f);
    ((int*)dst)[i] = (a & 255) | ((b & 255) << 8) | ((c & 255) << 16) | ((d & 255) << 24);
  }
}

// ---------------- GEMM: m97 structure (global_load_lds w=16, BK=32, unpadded LDS) ----
constexpr int BM = 128, BN = 128, BK = 32;

template <bool PROJ>
__global__ __launch_bounds__(256)
void gemm_kernel(const u16* __restrict__ Abase, const u16* __restrict__ Wbase,
                 const float* __restrict__ b0, const float* __restrict__ b1,
                 const float* __restrict__ b2, float* __restrict__ Cbase,
                 u32* __restrict__ sclu) {
  constexpr int K = NDM, N = NDM;
  const int z = PROJ ? blockIdx.z : 0;
  const u16* A = Abase + (size_t)z * NM * NDM;
  const u16* Wt = PROJ ? (Wbase + (size_t)z * NDM * NDM) : Wbase;
  const float* bias = PROJ ? (z == 0 ? b0 : z == 1 ? b1 : b2) : b0;
  float* C = PROJ ? (Cbase + (size_t)z * NM * NDM) : Cbase;
  const u32* slot_in = PROJ ? (sclu + z) : (sclu + 7);
  const u32* slot_w = PROJ ? (sclu + 3 + z) : (sclu + 6);

  __shared__ __align__(16) u16 As[BM][BK];   // 8 KB, contiguous (global_load_lds dest)
  __shared__ __align__(16) u16 Bs[BN][BK];
  __shared__ float rmax2[2][BM];

  const int tid = threadIdx.x;
  const int lane = tid & 63, wave = tid >> 6;
  const int wm = (wave & 1) * 64, wn = (wave >> 1) * 64;
  const int r16 = lane & 15, quad = lane >> 4;
  const int bm = blockIdx.x * BM, bn = blockIdx.y * BN;

  f32x4 acc[4][4] = {};

  const int lrow = lane >> 2, lcol = (lane & 3) * 8;  // staging: 16 rows/instr, 16B chunks
  for (int k0 = 0; k0 < K; k0 += BK) {
    __syncthreads();
#pragma unroll
    for (int p = 0; p < 2; p++) {
      int r = wave * 32 + p * 16;
      glds16(A + (size_t)(bm + r + lrow) * K + k0 + lcol, &As[r][0]);
      glds16(Wt + (size_t)(bn + r + lrow) * K + k0 + lcol, &Bs[r][0]);
    }
    __syncthreads();
    short8 af[4], bfr[4];
#pragma unroll
    for (int i = 0; i < 4; i++) af[i] = *(const short8*)(&As[wm + i * 16 + r16][quad * 8]);
#pragma unroll
    for (int j = 0; j < 4; j++) bfr[j] = *(const short8*)(&Bs[wn + j * 16 + r16][quad * 8]);
#pragma unroll
    for (int i = 0; i < 4; i++)
#pragma unroll
      for (int j = 0; j < 4; j++)
        acc[i][j] = __builtin_amdgcn_mfma_f32_16x16x32_bf16(af[i], bfr[j], acc[i][j], 0, 0, 0);
  }

  float s_in = fmaxf(fdec(*slot_in), QEPS) / 255.0f;
  float s_w = fmaxf(fdec(*slot_w), QEPS) / 127.0f;
  float sc = s_in * s_w;

  float bq[4];
#pragma unroll
  for (int j = 0; j < 4; j++) {
    int gc = bn + wn + j * 16 + r16;
    bq[j] = rintf(bias[gc] / sc) * sc;
  }
  // rows owned uniquely by (wave, i, quad, r) within the wn group; track |C| max per row
#pragma unroll
  for (int i = 0; i < 4; i++) {
#pragma unroll
    for (int r = 0; r < 4; r++) {
      int lr = wm + i * 16 + quad * 4 + r;  // == s index (bm % 128 == 0)
      int gr = bm + lr;
      float rm = 0.0f;
#pragma unroll
      for (int j = 0; j < 4; j++) {
        int gc = bn + wn + j * 16 + r16;
        float val = acc[i][j][r] * sc + bq[j];
        C[(size_t)gr * N + gc] = val;
        if (PROJ) rm = fmaxf(rm, fabsf(val));
      }
      if (PROJ) {
#pragma unroll
        for (int off = 1; off < 16; off <<= 1) rm = fmaxf(rm, __shfl_xor(rm, off));
        if (r16 == 0) rmax2[wave >> 1][lr] = rm;
      }
    }
  }
  if (PROJ) {
    __syncthreads();
    if (tid < BM) {
      float m = fmaxf(rmax2[0][tid], rmax2[1][tid]);
      atomicMax((int*)&sclu[8 + z * 128 + tid], __float_as_int(m));  // m >= 0
    }
  }
}

// ---------------- attention ----------------
// scores: int8 MFMA QK^T (exact) + softmax + normalized P fp32 out + global colmax
__global__ __launch_bounds__(256)
void attn_scores_kernel(const i8* __restrict__ qi8, const i8* __restrict__ ki8,
                        const u64* __restrict__ mb, const float* __restrict__ scl,
                        u32* __restrict__ sclu, float* __restrict__ Pn) {
  const int bh = blockIdx.x, b = bh >> 4, h = bh & 15;
  const int tid = threadIdx.x, lane = tid & 63, wave = tid >> 6;
  const int r16 = lane & 15, quad = lane >> 4;

  __shared__ __align__(16) i8 Qs[NS][80];  // 64B rows padded to 80
  __shared__ __align__(16) i8 Ks[NS][80];
  __shared__ float sqv[NS], skv[NS];
  __shared__ float cmw[4][NS];

  {
    int row = tid >> 1, half = (tid & 1) * 32;
    const i8* qp = qi8 + (size_t)(b * NS + row) * NDM + h * NDK + half;
    const i8* kp = ki8 + (size_t)(b * NS + row) * NDM + h * NDK + half;
    *(int4*)&Qs[row][half] = *(const int4*)qp;
    *(int4*)&Qs[row][half + 16] = *(const int4*)(qp + 16);
    *(int4*)&Ks[row][half] = *(const int4*)kp;
    *(int4*)&Ks[row][half + 16] = *(const int4*)(kp + 16);
    if (tid < NS) {
      sqv[tid] = fmaxf(scl[8 + tid], QEPS) / 127.0f;
      skv[tid] = fmaxf(scl[8 + 128 + tid], QEPS) / 127.0f;
    }
  }
  __syncthreads();

  const int rowbase = wave * 32;
  i32x4 acc[2][8] = {};
#pragma unroll
  for (int mt = 0; mt < 2; mt++) {
    i32x4 a = *(const i32x4*)&Qs[rowbase + mt * 16 + r16][quad * 16];
#pragma unroll
    for (int nt = 0; nt < 8; nt++) {
      i32x4 bfrag = *(const i32x4*)&Ks[nt * 16 + r16][quad * 16];
      acc[mt][nt] = __builtin_amdgcn_mfma_i32_16x16x64_i8(a, bfrag, acc[mt][nt], 0, 0, 0);
    }
  }

  float skc[8], cm[8];
#pragma unroll
  for (int nt = 0; nt < 8; nt++) { skc[nt] = skv[nt * 16 + r16]; cm[nt] = 0.0f; }

#pragma unroll
  for (int mt = 0; mt < 2; mt++) {
#pragma unroll
    for (int r = 0; r < 4; r++) {
      int row = rowbase + mt * 16 + quad * 4 + r;
      float sq = sqv[row];
      const u64* mrow = mb + ((size_t)b * NS + row) * 2;
      u64 m0 = mrow[0], m1 = mrow[1];
      float vals[8];
      float mx = -INFINITY;
#pragma unroll
      for (int nt = 0; nt < 8; nt++) {
        float v = (float)acc[mt][nt][r] * (sq * skc[nt]) * 0.125f;
        u64 bits = nt < 4 ? m0 : m1;
        if (((bits >> ((nt * 16 + r16) & 63)) & 1ull) == 0) v = -1e9f;
        vals[nt] = v;
        mx = fmaxf(mx, v);
      }
#pragma unroll
      for (int off = 1; off < 16; off <<= 1) mx = fmaxf(mx, __shfl_xor(mx, off));
      float sum = 0.0f;
#pragma unroll
      for (int nt = 0; nt < 8; nt++) { vals[nt] = __expf(vals[nt] - mx); sum += vals[nt]; }
#pragma unroll
      for (int off = 1; off < 16; off <<= 1) sum += __shfl_xor(sum, off);
      float* prow = Pn + ((size_t)bh * NS + row) * NS;
#pragma unroll
      for (int nt = 0; nt < 8; nt++) {
        float p = vals[nt] / sum;  // per-element division, matches jax softmax
        prow[nt * 16 + r16] = p;
        cm[nt] = fmaxf(cm[nt], p);
      }
    }
  }

#pragma unroll
  for (int nt = 0; nt < 8; nt++) {
    float c = cm[nt];
    c = fmaxf(c, __shfl_xor(c, 16));
    c = fmaxf(c, __shfl_xor(c, 32));
    if (quad == 0) cmw[wave][nt * 16 + r16] = c;
  }
  __syncthreads();
  if (tid < NS) {
    float c = fmaxf(fmaxf(cmw[0][tid], cmw[1][tid]), fmaxf(cmw[2][tid], cmw[3][tid]));
    atomicMax((int*)&sclu[392 + tid], __float_as_int(c));  // p >= 0
  }
}

// pv: read normalized P, quantize with colmax scales, bf16 hi/lo MFMA with scaled V
__global__ __launch_bounds__(256)
void attn_pv_kernel(const float* __restrict__ Pn, const i8* __restrict__ vi8,
                    const float* __restrict__ scl, float* __restrict__ xout,
                    u32* __restrict__ xmax_slot) {
  const int bh = blockIdx.x, b = bh >> 4, h = bh & 15;
  const int tid = threadIdx.x, lane = tid & 63, wave = tid >> 6;
  const int r16 = lane & 15, quad = lane >> 4;
  const int rowbase = wave * 32;

  __shared__ __align__(16) u16 Ps[NS][72];   // quantized p ints (bf16-exact)
  __shared__ __align__(16) u16 Vhi[64][72];  // V^T scaled by sp[j]*sv[j], hi part
  __shared__ __align__(16) u16 Vlo[64][72];
  __shared__ float spv[NS], svv[NS];

  if (tid < NS) {
    spv[tid] = fmaxf(scl[392 + tid], QEPS) / 127.0f;
    svv[tid] = fmaxf(scl[8 + 256 + tid], QEPS) / 127.0f;
  }

  f32x4 xacc[2][4] = {};
  for (int half = 0; half < 2; half++) {
    __syncthreads();
    {  // stage P half: thread -> (row, 32 cols)
      int row = tid >> 1, jl0 = (tid & 1) * 32;
      const float* prow = Pn + ((size_t)bh * NS + row) * NS + half * 64 + jl0;
#pragma unroll
      for (int c4 = 0; c4 < 8; c4++) {
        float4 p = *(const float4*)(prow + c4 * 4);
        int j = half * 64 + jl0 + c4 * 4;
        ushort4 o;
        o.x = f2bf(fminf(fmaxf(rintf(p.x / spv[j + 0]), -128.f), 127.f));
        o.y = f2bf(fminf(fmaxf(rintf(p.y / spv[j + 1]), -128.f), 127.f));
        o.z = f2bf(fminf(fmaxf(rintf(p.z / spv[j + 2]), -128.f), 127.f));
        o.w = f2bf(fminf(fmaxf(rintf(p.w / spv[j + 3]), -128.f), 127.f));
        *(ushort4*)&Ps[row][jl0 + c4 * 4] = o;
      }
    }
    {  // stage V half transposed: thread -> (j, 16 d)
      int jl = tid >> 2, d0 = (tid & 3) * 16;
      int j = half * 64 + jl;
      float g = spv[j] * svv[j];
      const i8* vp = vi8 + (size_t)(b * NS + j) * NDM + h * NDK + d0;
      int4 raw = *(const int4*)vp;
      const i8* rb = (const i8*)&raw;
#pragma unroll
      for (int d = 0; d < 16; d++) {
        float w = (float)rb[d] * g;
        u16 hi = f2bf(w);
        Vhi[d0 + d][jl] = hi;
        Vlo[d0 + d][jl] = f2bf(w - bf2f(hi));
      }
    }
    __syncthreads();
#pragma unroll
    for (int kk = 0; kk < 2; kk++) {
      short8 pa[2];
#pragma unroll
      for (int mt = 0; mt < 2; mt++)
        pa[mt] = *(const short8*)&Ps[rowbase + mt * 16 + r16][kk * 32 + quad * 8];
#pragma unroll
      for (int nt = 0; nt < 4; nt++) {
        short8 vh = *(const short8*)&Vhi[nt * 16 + r16][kk * 32 + quad * 8];
        short8 vl = *(const short8*)&Vlo[nt * 16 + r16][kk * 32 + quad * 8];
#pragma unroll
        for (int mt = 0; mt < 2; mt++) {
          xacc[mt][nt] = __builtin_amdgcn_mfma_f32_16x16x32_bf16(pa[mt], vh, xacc[mt][nt], 0, 0, 0);
          xacc[mt][nt] = __builtin_amdgcn_mfma_f32_16x16x32_bf16(pa[mt], vl, xacc[mt][nt], 0, 0, 0);
        }
      }
    }
  }

  float mx = -INFINITY;
#pragma unroll
  for (int mt = 0; mt < 2; mt++)
#pragma unroll
    for (int nt = 0; nt < 4; nt++)
#pragma unroll
      for (int r = 0; r < 4; r++) {
        int row = rowbase + mt * 16 + quad * 4 + r;
        xout[((size_t)b * NS + row) * NDM + h * NDK + nt * 16 + r16] = xacc[mt][nt][r];
        mx = fmaxf(mx, xacc[mt][nt][r]);
      }
#pragma unroll
  for (int off = 1; off < 64; off <<= 1) mx = fmaxf(mx, __shfl_xor(mx, off));
  if (lane == 0) atomicMax(xmax_slot, fenc(mx));
}

// ---------------- workspace layout ----------------
constexpr size_t OFF_SCL = 0;                                    // 8 KB
constexpr size_t OFF_MB  = 8192;                                 // 128 KB
constexpr size_t OFF_W   = OFF_MB + (size_t)NM * 16;             // 8 MB (4 x bf16 1024^2)
constexpr size_t OFF_XQ  = OFF_W + 4 * (size_t)NDM * NDM * 2;    // 48 MB (3 x bf16 act)
constexpr size_t OFF_PQ  = OFF_XQ + 3 * (size_t)NM * NDM * 2;    // 100 MB (3 x f32 proj)
constexpr size_t OFF_I8  = OFF_PQ + 3 * (size_t)NM * NDM * 4;    // 24 MB (3 x i8)
// Pn (67 MB) aliases projq+projk (dead after qkv_i8); x aliases projv

extern "C" void kernel_launch(void* const* d_in, const int* in_sizes, int n_in,
                              void* d_out, int out_size, void* d_ws, size_t ws_size,
                              hipStream_t stream) {
  const float* query = (const float*)d_in[0];
  const float* key = (const float*)d_in[1];
  const float* value = (const float*)d_in[2];
  const int* mask = (const int*)d_in[3];
  const float* Wq = (const float*)d_in[4]; const float* bq = (const float*)d_in[5];
  const float* Wk = (const float*)d_in[6]; const float* bk = (const float*)d_in[7];
  const float* Wv = (const float*)d_in[8]; const float* bv = (const float*)d_in[9];
  const float* Wo = (const float*)d_in[10]; const float* bo = (const float*)d_in[11];

  char* ws = (char*)d_ws;
  float* scl = (float*)(ws + OFF_SCL);
  u32* sclu = (u32*)scl;
  u64* mb = (u64*)(ws + OFF_MB);
  u16* wb = (u16*)(ws + OFF_W);       // wq|wk|wv|wo
  u16* wob = wb + 3 * (size_t)NDM * NDM;
  u16* xq = (u16*)(ws + OFF_XQ);      // xqq|xqk|xqv (xqq reused for x)
  float* proj = (float*)(ws + OFF_PQ);
  i8* qkv8 = (i8*)(ws + OFF_I8);
  float* Pn = proj;                              // aliases projq+projk (exact fit)
  float* xout = proj + 2 * (size_t)NM * NDM;     // aliases projv
  i8* vi8 = qkv8 + 2 * (size_t)NM * NDM;

  init_kernel<<<1, 256, 0, stream>>>(sclu);
  maskbits_kernel<<<NM / 4, 256, 0, stream>>>(mask, mb);
  fused_max_kernel<<<dim3(512, 7), 256, 0, stream>>>(query, key, value, Wq, Wk, Wv, Wo, sclu);
  quant_w_kernel<<<dim3(512, 4), 256, 0, stream>>>(Wq, Wk, Wv, Wo, wb, sclu);

  quant_u8_kernel<<<512, 256, 0, stream>>>(query, xq, sclu + 0);
  quant_u8_kernel<<<512, 256, 0, stream>>>(key, xq + (size_t)NM * NDM, sclu + 1);
  quant_u8_kernel<<<512, 256, 0, stream>>>(value, xq + 2 * (size_t)NM * NDM, sclu + 2);

  gemm_kernel<true><<<dim3(NM / BM, NDM / BN, 3), 256, 0, stream>>>(
      xq, wb, bq, bk, bv, proj, sclu);

  qkv_i8_kernel<<<dim3(512, 3), 256, 0, stream>>>(proj, qkv8, scl);

  attn_scores_kernel<<<NB * NH, 256, 0, stream>>>(qkv8, qkv8 + (size_t)NM * NDM, mb, scl,
                                                  sclu, Pn);
  attn_pv_kernel<<<NB * NH, 256, 0, stream>>>(Pn, vi8, scl, xout, sclu + 7);

  quant_u8_kernel<<<512, 256, 0, stream>>>(xout, xq, sclu + 7);
  gemm_kernel<false><<<dim3(NM / BM, NDM / BN, 1), 256, 0, stream>>>(
      xq, wob, bo, bo, bo, (float*)d_out, sclu);
}

// Round 4
// 431.304 us; speedup vs baseline: 2.1492x; 1.1007x over previous
//
#include <hip/hip_runtime.h>
#include <hip/hip_bf16.h>
#include <math.h>

typedef unsigned short u16;
typedef unsigned int u32;
typedef unsigned long long u64;
typedef signed char i8;

constexpr int NB = 64, NS = 128, NDM = 1024, NH = 16, NDK = 64;
constexpr int NM = NB * NS;  // 8192
constexpr float QEPS = 1e-8f;

typedef __attribute__((ext_vector_type(8))) short short8;
typedef __attribute__((ext_vector_type(4))) float f32x4;
typedef __attribute__((ext_vector_type(4))) int i32x4;

__device__ __forceinline__ u32 fenc(float f) {
  u32 u = __float_as_uint(f);
  return (u & 0x80000000u) ? ~u : (u | 0x80000000u);
}
__device__ __forceinline__ float fdec(u32 u) {
  u = (u & 0x80000000u) ? (u & 0x7FFFFFFFu) : ~u;
  return __uint_as_float(u);
}
// quantized values are small integers -> exact bf16 truncation
__device__ __forceinline__ u16 f2bf(float f) { return (u16)(__float_as_uint(f) >> 16); }
__device__ __forceinline__ float bf2f(u16 u) { return __uint_as_float(((u32)u) << 16); }

// async global->LDS, 16B per lane; lds dest = wave-uniform base + lane*16
__device__ __forceinline__ void glds16(const void* g, void* l) {
  __builtin_amdgcn_global_load_lds(
      (const __attribute__((address_space(1))) void*)(unsigned long long)(uintptr_t)g,
      (__attribute__((address_space(3))) void*)(u32)(uintptr_t)l, 16, 0, 0);
}

// ---- scale slots (u32/float at ws offset 0) ----
// [0..2] enc max(q,k,v)  [3..6] enc absmax(W*)  [7] enc max(x)
// [8..135] absmax_q per s; [136..263] absmax_k; [264..391] absmax_v (plain float bits)
// [392..519] colmax_p per j (plain float bits)

__global__ void init_kernel(u32* scl) {
  for (int i = threadIdx.x; i < 2048; i += blockDim.x) scl[i] = 0u;
}

// mask[B,S,S] int32 -> bitmask [B*S][2] u64
__global__ void maskbits_kernel(const int* __restrict__ mask, u64* __restrict__ mb) {
  int row = blockIdx.x * 4 + (threadIdx.x >> 6);
  int lane = threadIdx.x & 63;
  const int* mrow = mask + (size_t)row * NS;
  u64 b0 = __ballot(mrow[lane] != 0);
  u64 b1 = __ballot(mrow[64 + lane] != 0);
  if (lane == 0) { mb[row * 2] = b0; mb[row * 2 + 1] = b1; }
}

// fused 7-way max reduce: y=0..2 max(q,k,v); y=3..6 absmax(Wq..Wo)
__global__ void fused_max_kernel(const float* __restrict__ q, const float* __restrict__ k,
                                 const float* __restrict__ v, const float* __restrict__ w0,
                                 const float* __restrict__ w1, const float* __restrict__ w2,
                                 const float* __restrict__ w3, u32* __restrict__ sclu) {
  int y = blockIdx.y;
  const float* src; size_t n4; int ab;
  switch (y) {
    case 0: src = q; n4 = (size_t)NM * NDM / 4; ab = 0; break;
    case 1: src = k; n4 = (size_t)NM * NDM / 4; ab = 0; break;
    case 2: src = v; n4 = (size_t)NM * NDM / 4; ab = 0; break;
    case 3: src = w0; n4 = (size_t)NDM * NDM / 4; ab = 1; break;
    case 4: src = w1; n4 = (size_t)NDM * NDM / 4; ab = 1; break;
    case 5: src = w2; n4 = (size_t)NDM * NDM / 4; ab = 1; break;
    default: src = w3; n4 = (size_t)NDM * NDM / 4; ab = 1; break;
  }
  float m = -INFINITY;
  size_t stride = (size_t)gridDim.x * blockDim.x;
  for (size_t i = (size_t)blockIdx.x * blockDim.x + threadIdx.x; i < n4; i += stride) {
    float4 f = ((const float4*)src)[i];
    if (ab) { f.x = fabsf(f.x); f.y = fabsf(f.y); f.z = fabsf(f.z); f.w = fabsf(f.w); }
    m = fmaxf(m, fmaxf(fmaxf(f.x, f.y), fmaxf(f.z, f.w)));
  }
  for (int off = 32; off; off >>= 1) m = fmaxf(m, __shfl_down(m, off));
  __shared__ float sm[4];
  if ((threadIdx.x & 63) == 0) sm[threadIdx.x >> 6] = m;
  __syncthreads();
  if (threadIdx.x == 0) {
    float r = fmaxf(fmaxf(sm[0], sm[1]), fmaxf(sm[2], sm[3]));
    atomicMax(&sclu[y], fenc(r));
  }
}

// weight quant -> i8 (-127..127) + per-output-channel column sums (for u8 shift fix)
// block = one weight row (output channel); y = which matrix
__global__ __launch_bounds__(256)
void quant_w_i8_kernel(const float* __restrict__ w0, const float* __restrict__ w1,
                       const float* __restrict__ w2, const float* __restrict__ w3,
                       i8* __restrict__ dst, int* __restrict__ colsum,
                       const u32* __restrict__ sclu) {
  int y = blockIdx.y, row = blockIdx.x, tid = threadIdx.x;
  const float* src = (y == 0 ? w0 : y == 1 ? w1 : y == 2 ? w2 : w3) + (size_t)row * NDM;
  float s = fmaxf(fdec(sclu[3 + y]), QEPS) / 127.0f;
  float4 f = ((const float4*)src)[tid];
  int a = (int)fminf(fmaxf(rintf(f.x / s), -127.f), 127.f);
  int b = (int)fminf(fmaxf(rintf(f.y / s), -127.f), 127.f);
  int c = (int)fminf(fmaxf(rintf(f.z / s), -127.f), 127.f);
  int d = (int)fminf(fmaxf(rintf(f.w / s), -127.f), 127.f);
  ((int*)(dst + (size_t)y * NDM * NDM + (size_t)row * NDM))[tid] =
      (a & 255) | ((b & 255) << 8) | ((c & 255) << 16) | ((d & 255) << 24);
  int ssum = a + b + c + d;
  for (int off = 32; off; off >>= 1) ssum += __shfl_down(ssum, off);
  __shared__ int sm[4];
  if ((tid & 63) == 0) sm[tid >> 6] = ssum;
  __syncthreads();
  if (tid == 0) colsum[y * NDM + row] = sm[0] + sm[1] + sm[2] + sm[3];
}

// uint8 activation fake-quant -> shifted i8 (q-128); y selects source/slot/dst
__global__ void quant_a_kernel(const float* __restrict__ s0, const float* __restrict__ s1,
                               const float* __restrict__ s2, i8* __restrict__ dst,
                               const u32* __restrict__ sclu, int slot_base) {
  int y = blockIdx.y;
  const float* src = y == 0 ? s0 : y == 1 ? s1 : s2;
  i8* d = dst + (size_t)y * NM * NDM;
  float s = fmaxf(fdec(sclu[slot_base + y]), QEPS) / 255.0f;
  size_t n4 = (size_t)NM * NDM / 4;
  size_t stride = (size_t)gridDim.x * blockDim.x;
  for (size_t i = (size_t)blockIdx.x * blockDim.x + threadIdx.x; i < n4; i += stride) {
    float4 f = ((const float4*)src)[i];
    int a = (int)fminf(fmaxf(rintf(f.x / s), 0.f), 255.f) - 128;
    int b = (int)fminf(fmaxf(rintf(f.y / s), 0.f), 255.f) - 128;
    int c = (int)fminf(fmaxf(rintf(f.z / s), 0.f), 255.f) - 128;
    int e = (int)fminf(fmaxf(rintf(f.w / s), 0.f), 255.f) - 128;
    ((int*)d)[i] = (a & 255) | ((b & 255) << 8) | ((c & 255) << 16) | ((e & 255) << 24);
  }
}

// proj fp32 -> int8 with per-s scale; y=0..2 selects q/k/v
__global__ void qkv_i8_kernel(const float* __restrict__ projbase, i8* __restrict__ dstbase,
                              const float* __restrict__ scl) {
  int y = blockIdx.y;
  const float* src = projbase + (size_t)y * NM * NDM;
  i8* dst = dstbase + (size_t)y * NM * NDM;
  const float* sb = scl + 8 + y * 128;
  size_t n4 = (size_t)NM * NDM / 4;
  size_t stride = (size_t)gridDim.x * blockDim.x;
  for (size_t i = (size_t)blockIdx.x * blockDim.x + threadIdx.x; i < n4; i += stride) {
    int s_idx = (int)((i >> 8) & 127);
    float s = fmaxf(sb[s_idx], QEPS) / 127.0f;
    float4 f = ((const float4*)src)[i];
    int a = (int)fminf(fmaxf(rintf(f.x / s), -128.f), 127.f);
    int b = (int)fminf(fmaxf(rintf(f.y / s), -128.f), 127.f);
    int c = (int)fminf(fmaxf(rintf(f.z / s), -128.f), 127.f);
    int d = (int)fminf(fmaxf(rintf(f.w / s), -128.f), 127.f);
    ((int*)dst)[i] = (a & 255) | ((b & 255) << 8) | ((c & 255) << 16) | ((d & 255) << 24);
  }
}

// ---------------- GEMM: i8 MFMA, K=64/iter, m97 staging ----------------
constexpr int BM = 128, BN = 128, BK = 64;

template <bool PROJ>
__global__ __launch_bounds__(256)
void gemm_kernel(const i8* __restrict__ Abase, const i8* __restrict__ Wbase,
                 const int* __restrict__ colsum, const float* __restrict__ b0,
                 const float* __restrict__ b1, const float* __restrict__ b2,
                 float* __restrict__ Cbase, u32* __restrict__ sclu) {
  constexpr int K = NDM, N = NDM;
  const int z = PROJ ? blockIdx.z : 0;
  const i8* A = Abase + (size_t)z * NM * NDM;
  const i8* Wt = PROJ ? (Wbase + (size_t)z * NDM * NDM) : Wbase;
  const float* bias = PROJ ? (z == 0 ? b0 : z == 1 ? b1 : b2) : b0;
  float* C = PROJ ? (Cbase + (size_t)z * NM * NDM) : Cbase;
  const u32* slot_in = PROJ ? (sclu + z) : (sclu + 7);
  const u32* slot_w = PROJ ? (sclu + 3 + z) : (sclu + 6);
  const int* cs = colsum + (PROJ ? z : 3) * NDM;

  __shared__ __align__(16) i8 As[BM][BK];  // 8 KB, contiguous (global_load_lds dest)
  __shared__ __align__(16) i8 Bs[BN][BK];
  __shared__ float rmax2[2][BM];

  const int tid = threadIdx.x;
  const int lane = tid & 63, wave = tid >> 6;
  const int wm = (wave & 1) * 64, wn = (wave >> 1) * 64;
  const int r16 = lane & 15, quad = lane >> 4;
  const int bm = blockIdx.x * BM, bn = blockIdx.y * BN;

  i32x4 acc[4][4] = {};

  const int lrow = lane >> 2, lcol = (lane & 3) * 16;  // 16 rows per glds16, 64B rows
  for (int k0 = 0; k0 < K; k0 += BK) {
    __syncthreads();
#pragma unroll
    for (int p = 0; p < 2; p++) {
      int r = wave * 32 + p * 16;
      glds16(A + (size_t)(bm + r + lrow) * K + k0 + lcol, &As[r][0]);
      glds16(Wt + (size_t)(bn + r + lrow) * K + k0 + lcol, &Bs[r][0]);
    }
    __syncthreads();
    i32x4 af[4], bfr[4];
#pragma unroll
    for (int i = 0; i < 4; i++) af[i] = *(const i32x4*)(&As[wm + i * 16 + r16][quad * 16]);
#pragma unroll
    for (int j = 0; j < 4; j++) bfr[j] = *(const i32x4*)(&Bs[wn + j * 16 + r16][quad * 16]);
#pragma unroll
    for (int i = 0; i < 4; i++)
#pragma unroll
      for (int j = 0; j < 4; j++)
        acc[i][j] = __builtin_amdgcn_mfma_i32_16x16x64_i8(af[i], bfr[j], acc[i][j], 0, 0, 0);
  }

  float s_in = fmaxf(fdec(*slot_in), QEPS) / 255.0f;
  float s_w = fmaxf(fdec(*slot_w), QEPS) / 127.0f;
  float sc = s_in * s_w;

  float bq[4];
  int csj[4];
#pragma unroll
  for (int j = 0; j < 4; j++) {
    int gc = bn + wn + j * 16 + r16;
    bq[j] = rintf(bias[gc] / sc) * sc;
    csj[j] = cs[gc] << 7;  // +128 * colsum(W): undoes the x-128 input shift
  }
#pragma unroll
  for (int i = 0; i < 4; i++) {
#pragma unroll
    for (int r = 0; r < 4; r++) {
      int lr = wm + i * 16 + quad * 4 + r;
      int gr = bm + lr;
      float rm = 0.0f;
#pragma unroll
      for (int j = 0; j < 4; j++) {
        int gc = bn + wn + j * 16 + r16;
        float val = (float)(acc[i][j][r] + csj[j]) * sc + bq[j];
        C[(size_t)gr * N + gc] = val;
        if (PROJ) rm = fmaxf(rm, fabsf(val));
      }
      if (PROJ) {
#pragma unroll
        for (int off = 1; off < 16; off <<= 1) rm = fmaxf(rm, __shfl_xor(rm, off));
        if (r16 == 0) rmax2[wave >> 1][lr] = rm;
      }
    }
  }
  if (PROJ) {
    __syncthreads();
    if (tid < BM) {
      float m = fmaxf(rmax2[0][tid], rmax2[1][tid]);
      atomicMax((int*)&sclu[8 + z * 128 + tid], __float_as_int(m));  // m >= 0
    }
  }
}

// ---------------- attention ----------------
__global__ __launch_bounds__(256)
void attn_scores_kernel(const i8* __restrict__ qi8, const i8* __restrict__ ki8,
                        const u64* __restrict__ mb, const float* __restrict__ scl,
                        u32* __restrict__ sclu, float* __restrict__ Pn) {
  const int bh = blockIdx.x, b = bh >> 4, h = bh & 15;
  const int tid = threadIdx.x, lane = tid & 63, wave = tid >> 6;
  const int r16 = lane & 15, quad = lane >> 4;

  __shared__ __align__(16) i8 Qs[NS][80];
  __shared__ __align__(16) i8 Ks[NS][80];
  __shared__ float sqv[NS], skv[NS];
  __shared__ float cmw[4][NS];

  {
    int row = tid >> 1, half = (tid & 1) * 32;
    const i8* qp = qi8 + (size_t)(b * NS + row) * NDM + h * NDK + half;
    const i8* kp = ki8 + (size_t)(b * NS + row) * NDM + h * NDK + half;
    *(int4*)&Qs[row][half] = *(const int4*)qp;
    *(int4*)&Qs[row][half + 16] = *(const int4*)(qp + 16);
    *(int4*)&Ks[row][half] = *(const int4*)kp;
    *(int4*)&Ks[row][half + 16] = *(const int4*)(kp + 16);
    if (tid < NS) {
      sqv[tid] = fmaxf(scl[8 + tid], QEPS) / 127.0f;
      skv[tid] = fmaxf(scl[8 + 128 + tid], QEPS) / 127.0f;
    }
  }
  __syncthreads();

  const int rowbase = wave * 32;
  i32x4 acc[2][8] = {};
#pragma unroll
  for (int mt = 0; mt < 2; mt++) {
    i32x4 a = *(const i32x4*)&Qs[rowbase + mt * 16 + r16][quad * 16];
#pragma unroll
    for (int nt = 0; nt < 8; nt++) {
      i32x4 bfrag = *(const i32x4*)&Ks[nt * 16 + r16][quad * 16];
      acc[mt][nt] = __builtin_amdgcn_mfma_i32_16x16x64_i8(a, bfrag, acc[mt][nt], 0, 0, 0);
    }
  }

  float skc[8], cm[8];
#pragma unroll
  for (int nt = 0; nt < 8; nt++) { skc[nt] = skv[nt * 16 + r16]; cm[nt] = 0.0f; }

#pragma unroll
  for (int mt = 0; mt < 2; mt++) {
#pragma unroll
    for (int r = 0; r < 4; r++) {
      int row = rowbase + mt * 16 + quad * 4 + r;
      float sq = sqv[row];
      const u64* mrow = mb + ((size_t)b * NS + row) * 2;
      u64 m0 = mrow[0], m1 = mrow[1];
      float vals[8];
      float mx = -INFINITY;
#pragma unroll
      for (int nt = 0; nt < 8; nt++) {
        float v = (float)acc[mt][nt][r] * (sq * skc[nt]) * 0.125f;
        u64 bits = nt < 4 ? m0 : m1;
        if (((bits >> ((nt * 16 + r16) & 63)) & 1ull) == 0) v = -1e9f;
        vals[nt] = v;
        mx = fmaxf(mx, v);
      }
#pragma unroll
      for (int off = 1; off < 16; off <<= 1) mx = fmaxf(mx, __shfl_xor(mx, off));
      float sum = 0.0f;
#pragma unroll
      for (int nt = 0; nt < 8; nt++) { vals[nt] = __expf(vals[nt] - mx); sum += vals[nt]; }
#pragma unroll
      for (int off = 1; off < 16; off <<= 1) sum += __shfl_xor(sum, off);
      float* prow = Pn + ((size_t)bh * NS + row) * NS;
#pragma unroll
      for (int nt = 0; nt < 8; nt++) {
        float p = vals[nt] / sum;
        prow[nt * 16 + r16] = p;
        cm[nt] = fmaxf(cm[nt], p);
      }
    }
  }

#pragma unroll
  for (int nt = 0; nt < 8; nt++) {
    float c = cm[nt];
    c = fmaxf(c, __shfl_xor(c, 16));
    c = fmaxf(c, __shfl_xor(c, 32));
    if (quad == 0) cmw[wave][nt * 16 + r16] = c;
  }
  __syncthreads();
  if (tid < NS) {
    float c = fmaxf(fmaxf(cmw[0][tid], cmw[1][tid]), fmaxf(cmw[2][tid], cmw[3][tid]));
    atomicMax((int*)&sclu[392 + tid], __float_as_int(c));  // p >= 0
  }
}

__global__ __launch_bounds__(256)
void attn_pv_kernel(const float* __restrict__ Pn, const i8* __restrict__ vi8,
                    const float* __restrict__ scl, float* __restrict__ xout,
                    u32* __restrict__ xmax_slot) {
  const int bh = blockIdx.x, b = bh >> 4, h = bh & 15;
  const int tid = threadIdx.x, lane = tid & 63, wave = tid >> 6;
  const int r16 = lane & 15, quad = lane >> 4;
  const int rowbase = wave * 32;

  __shared__ __align__(16) u16 Ps[NS][72];
  __shared__ __align__(16) u16 Vhi[64][72];
  __shared__ __align__(16) u16 Vlo[64][72];
  __shared__ float spv[NS], svv[NS];

  if (tid < NS) {
    spv[tid] = fmaxf(scl[392 + tid], QEPS) / 127.0f;
    svv[tid] = fmaxf(scl[8 + 256 + tid], QEPS) / 127.0f;
  }

  f32x4 xacc[2][4] = {};
  for (int half = 0; half < 2; half++) {
    __syncthreads();
    {
      int row = tid >> 1, jl0 = (tid & 1) * 32;
      const float* prow = Pn + ((size_t)bh * NS + row) * NS + half * 64 + jl0;
#pragma unroll
      for (int c4 = 0; c4 < 8; c4++) {
        float4 p = *(const float4*)(prow + c4 * 4);
        int j = half * 64 + jl0 + c4 * 4;
        ushort4 o;
        o.x = f2bf(fminf(fmaxf(rintf(p.x / spv[j + 0]), -128.f), 127.f));
        o.y = f2bf(fminf(fmaxf(rintf(p.y / spv[j + 1]), -128.f), 127.f));
        o.z = f2bf(fminf(fmaxf(rintf(p.z / spv[j + 2]), -128.f), 127.f));
        o.w = f2bf(fminf(fmaxf(rintf(p.w / spv[j + 3]), -128.f), 127.f));
        *(ushort4*)&Ps[row][jl0 + c4 * 4] = o;
      }
    }
    {
      int jl = tid >> 2, d0 = (tid & 3) * 16;
      int j = half * 64 + jl;
      float g = spv[j] * svv[j];
      const i8* vp = vi8 + (size_t)(b * NS + j) * NDM + h * NDK + d0;
      int4 raw = *(const int4*)vp;
      const i8* rb = (const i8*)&raw;
#pragma unroll
      for (int d = 0; d < 16; d++) {
        float w = (float)rb[d] * g;
        u16 hi = f2bf(w);
        Vhi[d0 + d][jl] = hi;
        Vlo[d0 + d][jl] = f2bf(w - bf2f(hi));
      }
    }
    __syncthreads();
#pragma unroll
    for (int kk = 0; kk < 2; kk++) {
      short8 pa[2];
#pragma unroll
      for (int mt = 0; mt < 2; mt++)
        pa[mt] = *(const short8*)&Ps[rowbase + mt * 16 + r16][kk * 32 + quad * 8];
#pragma unroll
      for (int nt = 0; nt < 4; nt++) {
        short8 vh = *(const short8*)&Vhi[nt * 16 + r16][kk * 32 + quad * 8];
        short8 vl = *(const short8*)&Vlo[nt * 16 + r16][kk * 32 + quad * 8];
#pragma unroll
        for (int mt = 0; mt < 2; mt++) {
          xacc[mt][nt] = __builtin_amdgcn_mfma_f32_16x16x32_bf16(pa[mt], vh, xacc[mt][nt], 0, 0, 0);
          xacc[mt][nt] = __builtin_amdgcn_mfma_f32_16x16x32_bf16(pa[mt], vl, xacc[mt][nt], 0, 0, 0);
        }
      }
    }
  }

  float mx = -INFINITY;
#pragma unroll
  for (int mt = 0; mt < 2; mt++)
#pragma unroll
    for (int nt = 0; nt < 4; nt++)
#pragma unroll
      for (int r = 0; r < 4; r++) {
        int row = rowbase + mt * 16 + quad * 4 + r;
        xout[((size_t)b * NS + row) * NDM + h * NDK + nt * 16 + r16] = xacc[mt][nt][r];
        mx = fmaxf(mx, xacc[mt][nt][r]);
      }
#pragma unroll
  for (int off = 1; off < 64; off <<= 1) mx = fmaxf(mx, __shfl_xor(mx, off));
  if (lane == 0) atomicMax(xmax_slot, fenc(mx));
}

// ---------------- workspace layout ----------------
constexpr size_t OFF_SCL = 0;                                   // 8 KB (2048 u32)
constexpr size_t OFF_CS  = 8192;                                // colsum 4x1024 int = 16 KB
constexpr size_t OFF_MB  = OFF_CS + 4 * NDM * 4;                // mask bits 128 KB
constexpr size_t OFF_W   = OFF_MB + (size_t)NM * 16;            // i8 weights 4 MB
constexpr size_t OFF_XQ  = OFF_W + 4 * (size_t)NDM * NDM;       // i8 acts 3x8 MB
constexpr size_t OFF_PQ  = OFF_XQ + 3 * (size_t)NM * NDM;       // f32 proj 3x33.5 MB
constexpr size_t OFF_I8  = OFF_PQ + 3 * (size_t)NM * NDM * 4;   // attn i8 qkv 3x8 MB
// Pn (67 MB) aliases projq+projk (dead after qkv_i8); xout aliases projv

extern "C" void kernel_launch(void* const* d_in, const int* in_sizes, int n_in,
                              void* d_out, int out_size, void* d_ws, size_t ws_size,
                              hipStream_t stream) {
  const float* query = (const float*)d_in[0];
  const float* key = (const float*)d_in[1];
  const float* value = (const float*)d_in[2];
  const int* mask = (const int*)d_in[3];
  const float* Wq = (const float*)d_in[4]; const float* bq = (const float*)d_in[5];
  const float* Wk = (const float*)d_in[6]; const float* bk = (const float*)d_in[7];
  const float* Wv = (const float*)d_in[8]; const float* bv = (const float*)d_in[9];
  const float* Wo = (const float*)d_in[10]; const float* bo = (const float*)d_in[11];

  char* ws = (char*)d_ws;
  float* scl = (float*)(ws + OFF_SCL);
  u32* sclu = (u32*)scl;
  int* colsum = (int*)(ws + OFF_CS);
  u64* mb = (u64*)(ws + OFF_MB);
  i8* wb = (i8*)(ws + OFF_W);        // wq|wk|wv|wo
  i8* wob = wb + 3 * (size_t)NDM * NDM;
  i8* xq = (i8*)(ws + OFF_XQ);       // q|k|v shifted i8 (slot 0 reused for x)
  float* proj = (float*)(ws + OFF_PQ);
  i8* qkv8 = (i8*)(ws + OFF_I8);
  float* Pn = proj;
  float* xout = proj + 2 * (size_t)NM * NDM;
  i8* vi8 = qkv8 + 2 * (size_t)NM * NDM;

  init_kernel<<<1, 256, 0, stream>>>(sclu);
  maskbits_kernel<<<NM / 4, 256, 0, stream>>>(mask, mb);
  fused_max_kernel<<<dim3(512, 7), 256, 0, stream>>>(query, key, value, Wq, Wk, Wv, Wo, sclu);
  quant_w_i8_kernel<<<dim3(NDM, 4), 256, 0, stream>>>(Wq, Wk, Wv, Wo, wb, colsum, sclu);
  quant_a_kernel<<<dim3(512, 3), 256, 0, stream>>>(query, key, value, xq, sclu, 0);

  gemm_kernel<true><<<dim3(NM / BM, NDM / BN, 3), 256, 0, stream>>>(
      xq, wb, colsum, bq, bk, bv, proj, sclu);

  qkv_i8_kernel<<<dim3(512, 3), 256, 0, stream>>>(proj, qkv8, scl);

  attn_scores_kernel<<<NB * NH, 256, 0, stream>>>(qkv8, qkv8 + (size_t)NM * NDM, mb, scl,
                                                  sclu, Pn);
  attn_pv_kernel<<<NB * NH, 256, 0, stream>>>(Pn, vi8, scl, xout, sclu + 7);

  quant_a_kernel<<<dim3(512, 1), 256, 0, stream>>>(xout, xout, xout, xq, sclu, 7);
  gemm_kernel<false><<<dim3(NM / BM, NDM / BN, 1), 256, 0, stream>>>(
      xq, wob, colsum, bo, bo, bo, (float*)d_out, sclu);
}